// Round 8
// baseline (3358.911 us; speedup 1.0000x reference)
//
#include <hip/hip_runtime.h>
#include <hip/hip_fp16.h>
#include <math.h>

#define B_ 64
#define T_ 512

typedef _Float16 h2_t __attribute__((ext_vector_type(2)));

__device__ __forceinline__ float fdot2u(unsigned int a, unsigned int b, float c) {
#if __has_builtin(__builtin_amdgcn_fdot2)
    return __builtin_amdgcn_fdot2(__builtin_bit_cast(h2_t, a),
                                  __builtin_bit_cast(h2_t, b), c, false);
#else
    const __half2 ah = __builtin_bit_cast(__half2, a);
    const __half2 bh = __builtin_bit_cast(__half2, b);
    const float2 af = __half22float2(ah), bf = __half22float2(bh);
    return c + af.x * bf.x + af.y * bf.y;
#endif
}
__device__ __forceinline__ unsigned int pack_h2(float x, float y) {
    const __half2 h = __float22half2_rn(make_float2(x, y));
    return __builtin_bit_cast(unsigned int, h);
}
__device__ __forceinline__ float ubits(unsigned int a) { return __builtin_bit_cast(float, a); }
__device__ __forceinline__ unsigned short f2h_bits(float x) {
    return __builtin_bit_cast(unsigned short, (_Float16)x);
}
__device__ __forceinline__ float h2f_bits(unsigned int bits) {
    return (float)__builtin_bit_cast(_Float16, (unsigned short)(bits & 0xffffu));
}

__device__ __forceinline__ float fsig(float z) { return 1.f / (1.f + __expf(-z)); }
__device__ __forceinline__ float ftanh(float z) {
    const float e = __expf(2.f * z);
    return 1.f - 2.f / (e + 1.f);
}

// LDS-only barrier: lgkmcnt(0) + s_barrier, no vmcnt drain (v12-proven).
__device__ __forceinline__ void bar_lds() {
    asm volatile("s_waitcnt lgkmcnt(0)" ::: "memory");
    __builtin_amdgcn_s_barrier();
    asm volatile("" ::: "memory");
}

// ---------------------------------------------------------------------------
// GEMM v2: C[M,N] = (A[M,K]*mask)@W[K,N] + bias, packed-fp16 dot2 inner loop.
// 64x64 tile, TK=32 (16 k-pairs), 256 threads, 4x4 microtile. (unchanged)
// ---------------------------------------------------------------------------
__global__ __launch_bounds__(256) void gemm_mask_f16(
    const float* __restrict__ A, const float* __restrict__ W,
    const float* __restrict__ bias, const float* __restrict__ mask,
    float* __restrict__ C, int M, int N, int K)
{
    const int TM = 64, TN = 64, TK = 32, KP = 16;
    __shared__ __align__(16) unsigned int As2[KP][68];
    __shared__ __align__(16) unsigned int Bs2[KP][68];

    const int tid = threadIdx.x;
    const int bn = blockIdx.x;
    const int bm = blockIdx.y;
    const int row0 = bm * TM;
    const int b = row0 / T_;

    const int ty = tid >> 4;
    const int tx = tid & 15;
    const int m0 = ty * 4;
    const int n0 = tx * 4;

    float acc[4][4];
#pragma unroll
    for (int i = 0; i < 4; i++)
#pragma unroll
        for (int j = 0; j < 4; j++) acc[i][j] = 0.f;

    for (int kk = 0; kk < K; kk += TK) {
        {
            const int m = tid >> 2;
            const int kq = (tid & 3) * 8;
            const float4 mv0 = *(const float4*)(mask + (size_t)b * K + kk + kq);
            const float4 mv1 = *(const float4*)(mask + (size_t)b * K + kk + kq + 4);
            const float4 a0 = *(const float4*)(A + (size_t)(row0 + m) * K + kk + kq);
            const float4 a1 = *(const float4*)(A + (size_t)(row0 + m) * K + kk + kq + 4);
            As2[kq / 2 + 0][m] = pack_h2(a0.x * mv0.x, a0.y * mv0.y);
            As2[kq / 2 + 1][m] = pack_h2(a0.z * mv0.z, a0.w * mv0.w);
            As2[kq / 2 + 2][m] = pack_h2(a1.x * mv1.x, a1.y * mv1.y);
            As2[kq / 2 + 3][m] = pack_h2(a1.z * mv1.z, a1.w * mv1.w);
        }
        {
            const int kp = tid >> 4;
            const int nq = (tid & 15) * 4;
            const float4 w0 = *(const float4*)(W + (size_t)(kk + 2 * kp) * N + bn * TN + nq);
            const float4 w1 = *(const float4*)(W + (size_t)(kk + 2 * kp + 1) * N + bn * TN + nq);
            uint4 pv;
            pv.x = pack_h2(w0.x, w1.x);
            pv.y = pack_h2(w0.y, w1.y);
            pv.z = pack_h2(w0.z, w1.z);
            pv.w = pack_h2(w0.w, w1.w);
            *(uint4*)&Bs2[kp][nq] = pv;
        }
        __syncthreads();

#pragma unroll
        for (int kp = 0; kp < KP; kp++) {
            const uint4 a4 = *(const uint4*)&As2[kp][m0];
            const uint4 b4 = *(const uint4*)&Bs2[kp][n0];
            acc[0][0] = fdot2u(a4.x, b4.x, acc[0][0]); acc[0][1] = fdot2u(a4.x, b4.y, acc[0][1]);
            acc[0][2] = fdot2u(a4.x, b4.z, acc[0][2]); acc[0][3] = fdot2u(a4.x, b4.w, acc[0][3]);
            acc[1][0] = fdot2u(a4.y, b4.x, acc[1][0]); acc[1][1] = fdot2u(a4.y, b4.y, acc[1][1]);
            acc[1][2] = fdot2u(a4.y, b4.z, acc[1][2]); acc[1][3] = fdot2u(a4.y, b4.w, acc[1][3]);
            acc[2][0] = fdot2u(a4.z, b4.x, acc[2][0]); acc[2][1] = fdot2u(a4.z, b4.y, acc[2][1]);
            acc[2][2] = fdot2u(a4.z, b4.z, acc[2][2]); acc[2][3] = fdot2u(a4.z, b4.w, acc[2][3]);
            acc[3][0] = fdot2u(a4.w, b4.x, acc[3][0]); acc[3][1] = fdot2u(a4.w, b4.y, acc[3][1]);
            acc[3][2] = fdot2u(a4.w, b4.z, acc[3][2]); acc[3][3] = fdot2u(a4.w, b4.w, acc[3][3]);
        }
        __syncthreads();
    }

    const float4 bv = *(const float4*)(bias + bn * TN + n0);
#pragma unroll
    for (int i = 0; i < 4; i++) {
        float4 v;
        v.x = acc[i][0] + bv.x;
        v.y = acc[i][1] + bv.y;
        v.z = acc[i][2] + bv.z;
        v.w = acc[i][3] + bv.w;
        *(float4*)&C[(size_t)(row0 + m0 + i) * N + bn * TN + n0] = v;
    }
}

// ---------------------------------------------------------------------------
// LSTM recurrence v17 = v14/v15 2-stream pipeline + v16's register pin.
// r7 evidence: v16's three dispatches all run ~705us (step ~3305cy) despite
// 2x differences in VALU work and HBM traffic -> ~2/3 of the step is the
// synchronous exchange chain (cell -> publish -> L2 visibility -> poll ->
// barrier + sibling skew), which compute optimization cannot touch. The
// 2-stream pipeline (v14, correctness-proven twice) hides stream A's
// exchange under stream B's dot -- but it ran with ur[32] SPILLED (VGPR 60 <
// 64 needed; VALUBusy 6%). v16 proved the asm pin forces residency where
// launch_bounds alone is ignored. v17 = v15 source + pin.
// Success signature: VGPR_Count >= ~105. Expected: phase ~= max(cell+RT,
// dot) ~= 850cy; per-stream step = 2 phases ~= 1700cy -> ~400-600us/dispatch.
// ---------------------------------------------------------------------------
template <int HN, bool F16>
__global__ __launch_bounds__(768, 3) void lstm_rec_v17(
    const float* __restrict__ xz,       // [B, T, 4*HN]
    const float* __restrict__ U,        // [HN, 4*HN]
    float* __restrict__ hout,           // [B, T, HN] or nullptr
    float* __restrict__ out_last,       // [B, HN] or nullptr
    unsigned int* __restrict__ hbuf)    // [2][B_*HN] tagged words
{
    constexpr int GATES = 4 * HN;
    constexpr int COLS = HN;            // gate-columns per (b,q) unit
    constexpr int CP = COLS / 2;        // col-pairs (128 / 64)
    constexpr int DOTT = 512;           // dot threads (waves 1-8)
    constexpr int NKG = DOTT / CP;      // k-groups (4 / 8)
    constexpr int KH = HN / NKG;        // k per group (64 / 16)
    constexpr int HB = HN / 4;          // units per quarter (64 / 32)
    constexpr int KWORDS = F16 ? HN / 2 : HN;   // hW words (128 / 128)
    constexpr int WPT = F16 ? KH / 2 : KH;      // ur words/thread (32 / 16)
    constexpr int COLSP = COLS + 2;     // padded col stride (even: float2 ok)
    constexpr int NR = 3 * HB / 2;      // remote qwords (96 / 48)

    __shared__ __align__(16) unsigned int hWA[KWORDS];
    __shared__ __align__(16) unsigned int hWB[KWORDS];
    __shared__ __align__(16) float zpA[NKG * COLSP];
    __shared__ __align__(16) float zpB[NKG * COLSP];

    const int tid = threadIdx.x;
    const int q  = blockIdx.x >> 5;     // quarter 0..3
    const int bp = blockIdx.x & 31;     // batch pair; siblings (bp, q') at
    const int bA = 2 * bp;              // blocks q'*32+bp -> all == bp mod 8
    const int bB = 2 * bp + 1;          // -> same XCD (L2-local exchange)

    const bool is_cell = (tid < HB);
    const int  dtid    = tid - 64;
    const bool is_dot  = (dtid >= 0 && dtid < DOTT);
    const int  ptid    = tid - (64 + DOTT);
    const bool is_poll = (ptid >= 0 && ptid < NR);

    // dot-thread geometry
    const int cp = dtid & (CP - 1);
    const int kq = dtid / CP;           // wave-uniform (CP % 64 == 0)
    const int c0 = 2 * cp;
    const int group = c0 / HB;
    const int gcol = group * HN + q * HB + (c0 % HB);

    // ---- one-time: U slice into registers (dot threads only), then PIN ----
    uint2 ur[WPT];
    if (is_dot) {
#pragma unroll
        for (int j = 0; j < WPT; ++j) {
            const int w = kq * WPT + j;
            if constexpr (F16) {
                const float2 r0 = *(const float2*)(U + (size_t)(2 * w) * GATES + gcol);
                const float2 r1 = *(const float2*)(U + (size_t)(2 * w + 1) * GATES + gcol);
                ur[j].x = pack_h2(r0.x, r1.x);
                ur[j].y = pack_h2(r0.y, r1.y);
            } else {
                const float2 r0 = *(const float2*)(U + (size_t)w * GATES + gcol);
                ur[j].x = __builtin_bit_cast(unsigned int, r0.x);
                ur[j].y = __builtin_bit_cast(unsigned int, r0.y);
            }
        }
    }
    // Pin (v16-proven): compiler cannot rematerialize/sink the U loads past
    // this point; ur must live in VGPRs for the whole T-loop. Without this,
    // the allocator re-streams U from L2 every phase (v14/v15: VGPR 60,
    // VALUBusy 6%, 1090us).
#pragma unroll
    for (int j = 0; j < WPT; ++j)
        asm volatile("" : "+v"(ur[j].x), "+v"(ur[j].y));

    // ---- zero init: hW = h(-1) = 0, zpart = 0 (first cell adds zeros) ----
    for (int i = tid; i < KWORDS; i += 768) { hWA[i] = 0u; hWB[i] = 0u; }
    for (int i = tid; i < NKG * COLSP; i += 768) { zpA[i] = 0.f; zpB[i] = 0.f; }

    // cell-lane state (wave0 lanes < HB): unit u = tid of both streams
    float z4A[4] = {0.f, 0.f, 0.f, 0.f};
    float z4B[4] = {0.f, 0.f, 0.f, 0.f};
    float cstA = 0.f, cstB = 0.f;
    if (is_cell) {
#pragma unroll
        for (int g = 0; g < 4; ++g) {
            z4A[g] = xz[(size_t)bA * T_ * GATES + (size_t)g * HN + q * HB + tid];
            z4B[g] = xz[(size_t)bB * T_ * GATES + (size_t)g * HN + q * HB + tid];
        }
    }
    __syncthreads();   // one-time init barrier (full semantics, off hot path)

    // ---- phase bodies ----
    auto do_dot = [&](const unsigned int* hWr, float* zpw) {
        float acc0 = 0.f, acc1 = 0.f;
#pragma unroll
        for (int j = 0; j < WPT; j += 4) {
            const int w = kq * WPT + j;
            const uint4 hw4 = *(const uint4*)&hWr[w];   // wave-uniform broadcast
            if constexpr (F16) {
                acc0 = fdot2u(ur[j + 0].x, hw4.x, acc0); acc1 = fdot2u(ur[j + 0].y, hw4.x, acc1);
                acc0 = fdot2u(ur[j + 1].x, hw4.y, acc0); acc1 = fdot2u(ur[j + 1].y, hw4.y, acc1);
                acc0 = fdot2u(ur[j + 2].x, hw4.z, acc0); acc1 = fdot2u(ur[j + 2].y, hw4.z, acc1);
                acc0 = fdot2u(ur[j + 3].x, hw4.w, acc0); acc1 = fdot2u(ur[j + 3].y, hw4.w, acc1);
            } else {
                acc0 += ubits(ur[j + 0].x) * ubits(hw4.x); acc1 += ubits(ur[j + 0].y) * ubits(hw4.x);
                acc0 += ubits(ur[j + 1].x) * ubits(hw4.y); acc1 += ubits(ur[j + 1].y) * ubits(hw4.y);
                acc0 += ubits(ur[j + 2].x) * ubits(hw4.z); acc1 += ubits(ur[j + 2].y) * ubits(hw4.z);
                acc0 += ubits(ur[j + 3].x) * ubits(hw4.w); acc1 += ubits(ur[j + 3].y) * ubits(hw4.w);
            }
        }
        // [kq][col] layout: lane-contiguous float2 -> conflict-free ds_write_b64
        *(float2*)&zpw[kq * COLSP + c0] = make_float2(acc0, acc1);
    };

    auto do_cell = [&](const float* zpr, float* z4l, float& cst, int t,
                       int bS, unsigned int* hWl) {
        float zg[4];
#pragma unroll
        for (int g = 0; g < 4; ++g) {
            float zs = z4l[g];
#pragma unroll
            for (int r = 0; r < NKG; ++r) zs += zpr[r * COLSP + g * HB + tid];
            zg[g] = zs;
        }
        if (t + 1 < T_) {   // prefetch next xz (consumed 2 phases later)
            const float* xzc = xz + (size_t)bS * T_ * GATES + (size_t)(t + 1) * GATES
                             + q * HB + tid;
#pragma unroll
            for (int g = 0; g < 4; ++g) z4l[g] = xzc[(size_t)g * HN];
        }
        const float ig = fsig(zg[0]);
        const float fg = fsig(zg[1]);
        const float gg = ftanh(zg[2]);
        const float og = fsig(zg[3]);
        cst = fg * cst + ig * gg;
        const float hnew = og * ftanh(cst);

        if (hout) hout[((size_t)bS * T_ + t) * HN + q * HB + tid] = hnew;
        if (t == T_ - 1) {
            if (out_last) out_last[(size_t)bS * HN + q * HB + tid] = hnew;
        } else {
            unsigned int* hslot = hbuf + (size_t)(t & 1) * B_ * HN + bS * HN;
            const unsigned int tag = (unsigned int)(t + 1);
            const unsigned short h16 = f2h_bits(hnew);
            __hip_atomic_store(&hslot[q * HB + tid],
                               (tag << 16) | (unsigned int)h16,
                               __ATOMIC_RELAXED, __HIP_MEMORY_SCOPE_AGENT);
            if constexpr (F16) {
                reinterpret_cast<unsigned short*>(hWl)[q * HB + tid] = h16;
            } else {
                hWl[q * HB + tid] = __builtin_bit_cast(unsigned int, hnew);
            }
        }
    };

    auto do_poll = [&](int t, int bS, unsigned int* hWl) {   // only t < T_-1
        unsigned int* hslot = hbuf + (size_t)(t & 1) * B_ * HN + bS * HN;
        const unsigned int tag = (unsigned int)(t + 1);
        const int qp0 = q * (HB / 2);
        const int p = ptid + (ptid >= qp0 ? (HB / 2) : 0);   // skip own quarter
        const unsigned long long* hq = (const unsigned long long*)hslot;
        unsigned long long v = __hip_atomic_load(&hq[p],
            __ATOMIC_RELAXED, __HIP_MEMORY_SCOPE_AGENT);
        while (((v >> 16) & 0xffffu) != tag || (v >> 48) != tag)
            v = __hip_atomic_load(&hq[p],
                __ATOMIC_RELAXED, __HIP_MEMORY_SCOPE_AGENT);
        if constexpr (F16) {
            hWl[p] = (unsigned int)(v & 0xffffu) |
                     ((unsigned int)((v >> 32) & 0xffffu) << 16);
        } else {
            hWl[2 * p + 0] = __builtin_bit_cast(unsigned int, h2f_bits((unsigned int)v));
            hWl[2 * p + 1] = __builtin_bit_cast(unsigned int, h2f_bits((unsigned int)(v >> 32)));
        }
    };

#pragma unroll 1
    for (int t = 0; t < T_; ++t) {
        // phase even: cell_A(t) || dot_B(t) [h_B(t-1)] || poll_A(tag t+1)
        if (is_cell)      do_cell(zpA, z4A, cstA, t, bA, hWA);
        else if (is_dot)  do_dot(hWB, zpB);
        else if (is_poll && t < T_ - 1) do_poll(t, bA, hWA);
        bar_lds();
        // phase odd: cell_B(t) || dot_A(t+1) [h_A(t)] || poll_B(tag t+1)
        if (is_cell)      do_cell(zpB, z4B, cstB, t, bB, hWB);
        else if (is_dot)  { if (t + 1 < T_) do_dot(hWA, zpA); }
        else if (is_poll && t < T_ - 1) do_poll(t, bB, hWB);
        bar_lds();
    }
}

// ---------------------------------------------------------------------------
// Launch
// ---------------------------------------------------------------------------
extern "C" void kernel_launch(void* const* d_in, const int* in_sizes, int n_in,
                              void* d_out, int out_size, void* d_ws, size_t ws_size,
                              hipStream_t stream)
{
    const float* x  = (const float*)d_in[0];
    const float* W0 = (const float*)d_in[1];
    const float* U0 = (const float*)d_in[2];
    const float* b0 = (const float*)d_in[3];
    const float* W1 = (const float*)d_in[4];
    const float* U1 = (const float*)d_in[5];
    const float* b1 = (const float*)d_in[6];
    const float* W2 = (const float*)d_in[7];
    const float* U2 = (const float*)d_in[8];
    const float* b2 = (const float*)d_in[9];
    const float* m0 = (const float*)d_in[10];
    const float* m1 = (const float*)d_in[11];
    const float* m2 = (const float*)d_in[12];
    float* out = (float*)d_out;

    // workspace layout:
    //   xz    : 134217728 B   (64*512*1024 floats, reused by all 3 layers)
    //   h0    :  33554432 B
    //   h1    :  33554432 B
    //   hbuf  : 3 regions x 131072 B (2 x 64 x 256 tagged words per layer)
    char* ws = (char*)d_ws;
    float* xz = (float*)ws;
    float* h0 = (float*)(ws + 134217728);
    float* h1 = (float*)(ws + 134217728 + 33554432);
    unsigned int* hb0 = (unsigned int*)(ws + 134217728 + 2 * 33554432);
    unsigned int* hb1 = hb0 + 2 * B_ * 256;
    unsigned int* hb2 = hb1 + 2 * B_ * 256;

    const int M = B_ * T_;  // 32768

    // Layer 0
    gemm_mask_f16<<<dim3(1024 / 64, M / 64), 256, 0, stream>>>(x, W0, b0, m0, xz, M, 1024, 128);
    lstm_rec_v17<256, true><<<128, 768, 0, stream>>>(xz, U0, h0, nullptr, hb0);

    // Layer 1
    gemm_mask_f16<<<dim3(1024 / 64, M / 64), 256, 0, stream>>>(h0, W1, b1, m1, xz, M, 1024, 256);
    lstm_rec_v17<256, true><<<128, 768, 0, stream>>>(xz, U1, h1, nullptr, hb1);

    // Layer 2 (H=128, f32 dot, fp16 exchange), emit last h only
    gemm_mask_f16<<<dim3(512 / 64, M / 64), 256, 0, stream>>>(h1, W2, b2, m2, xz, M, 512, 256);
    lstm_rec_v17<128, false><<<128, 768, 0, stream>>>(xz, U2, nullptr, out, hb2);
}

// Round 9
// 2111.870 us; speedup vs baseline: 1.5905x; 1.5905x over previous
//
#include <hip/hip_runtime.h>
#include <hip/hip_fp16.h>
#include <math.h>

#define B_ 64
#define T_ 512

typedef _Float16 h2_t __attribute__((ext_vector_type(2)));

__device__ __forceinline__ float fdot2u(unsigned int a, unsigned int b, float c) {
#if __has_builtin(__builtin_amdgcn_fdot2)
    return __builtin_amdgcn_fdot2(__builtin_bit_cast(h2_t, a),
                                  __builtin_bit_cast(h2_t, b), c, false);
#else
    const __half2 ah = __builtin_bit_cast(__half2, a);
    const __half2 bh = __builtin_bit_cast(__half2, b);
    const float2 af = __half22float2(ah), bf = __half22float2(bh);
    return c + af.x * bf.x + af.y * bf.y;
#endif
}
__device__ __forceinline__ unsigned int pack_h2(float x, float y) {
    const __half2 h = __float22half2_rn(make_float2(x, y));
    return __builtin_bit_cast(unsigned int, h);
}
__device__ __forceinline__ float ubits(unsigned int a) { return __builtin_bit_cast(float, a); }
__device__ __forceinline__ unsigned short f2h_bits(float x) {
    return __builtin_bit_cast(unsigned short, (_Float16)x);
}
__device__ __forceinline__ float h2f_bits(unsigned int bits) {
    return (float)__builtin_bit_cast(_Float16, (unsigned short)(bits & 0xffffu));
}

__device__ __forceinline__ float fsig(float z) { return 1.f / (1.f + __expf(-z)); }
__device__ __forceinline__ float ftanh(float z) {
    const float e = __expf(2.f * z);
    return 1.f - 2.f / (e + 1.f);
}

// LDS-only barrier: lgkmcnt(0) + s_barrier, no vmcnt drain (v12-proven).
__device__ __forceinline__ void bar_lds() {
    asm volatile("s_waitcnt lgkmcnt(0)" ::: "memory");
    __builtin_amdgcn_s_barrier();
    asm volatile("" ::: "memory");
}

// ---------------------------------------------------------------------------
// GEMM v2: C[M,N] = (A[M,K]*mask)@W[K,N] + bias, packed-fp16 dot2 inner loop.
// 64x64 tile, TK=32 (16 k-pairs), 256 threads, 4x4 microtile. (unchanged)
// ---------------------------------------------------------------------------
__global__ __launch_bounds__(256) void gemm_mask_f16(
    const float* __restrict__ A, const float* __restrict__ W,
    const float* __restrict__ bias, const float* __restrict__ mask,
    float* __restrict__ C, int M, int N, int K)
{
    const int TM = 64, TN = 64, TK = 32, KP = 16;
    __shared__ __align__(16) unsigned int As2[KP][68];
    __shared__ __align__(16) unsigned int Bs2[KP][68];

    const int tid = threadIdx.x;
    const int bn = blockIdx.x;
    const int bm = blockIdx.y;
    const int row0 = bm * TM;
    const int b = row0 / T_;

    const int ty = tid >> 4;
    const int tx = tid & 15;
    const int m0 = ty * 4;
    const int n0 = tx * 4;

    float acc[4][4];
#pragma unroll
    for (int i = 0; i < 4; i++)
#pragma unroll
        for (int j = 0; j < 4; j++) acc[i][j] = 0.f;

    for (int kk = 0; kk < K; kk += TK) {
        {
            const int m = tid >> 2;
            const int kq = (tid & 3) * 8;
            const float4 mv0 = *(const float4*)(mask + (size_t)b * K + kk + kq);
            const float4 mv1 = *(const float4*)(mask + (size_t)b * K + kk + kq + 4);
            const float4 a0 = *(const float4*)(A + (size_t)(row0 + m) * K + kk + kq);
            const float4 a1 = *(const float4*)(A + (size_t)(row0 + m) * K + kk + kq + 4);
            As2[kq / 2 + 0][m] = pack_h2(a0.x * mv0.x, a0.y * mv0.y);
            As2[kq / 2 + 1][m] = pack_h2(a0.z * mv0.z, a0.w * mv0.w);
            As2[kq / 2 + 2][m] = pack_h2(a1.x * mv1.x, a1.y * mv1.y);
            As2[kq / 2 + 3][m] = pack_h2(a1.z * mv1.z, a1.w * mv1.w);
        }
        {
            const int kp = tid >> 4;
            const int nq = (tid & 15) * 4;
            const float4 w0 = *(const float4*)(W + (size_t)(kk + 2 * kp) * N + bn * TN + nq);
            const float4 w1 = *(const float4*)(W + (size_t)(kk + 2 * kp + 1) * N + bn * TN + nq);
            uint4 pv;
            pv.x = pack_h2(w0.x, w1.x);
            pv.y = pack_h2(w0.y, w1.y);
            pv.z = pack_h2(w0.z, w1.z);
            pv.w = pack_h2(w0.w, w1.w);
            *(uint4*)&Bs2[kp][nq] = pv;
        }
        __syncthreads();

#pragma unroll
        for (int kp = 0; kp < KP; kp++) {
            const uint4 a4 = *(const uint4*)&As2[kp][m0];
            const uint4 b4 = *(const uint4*)&Bs2[kp][n0];
            acc[0][0] = fdot2u(a4.x, b4.x, acc[0][0]); acc[0][1] = fdot2u(a4.x, b4.y, acc[0][1]);
            acc[0][2] = fdot2u(a4.x, b4.z, acc[0][2]); acc[0][3] = fdot2u(a4.x, b4.w, acc[0][3]);
            acc[1][0] = fdot2u(a4.y, b4.x, acc[1][0]); acc[1][1] = fdot2u(a4.y, b4.y, acc[1][1]);
            acc[1][2] = fdot2u(a4.y, b4.z, acc[1][2]); acc[1][3] = fdot2u(a4.y, b4.w, acc[1][3]);
            acc[2][0] = fdot2u(a4.z, b4.x, acc[2][0]); acc[2][1] = fdot2u(a4.z, b4.y, acc[2][1]);
            acc[2][2] = fdot2u(a4.z, b4.z, acc[2][2]); acc[2][3] = fdot2u(a4.z, b4.w, acc[2][3]);
            acc[3][0] = fdot2u(a4.w, b4.x, acc[3][0]); acc[3][1] = fdot2u(a4.w, b4.y, acc[3][1]);
            acc[3][2] = fdot2u(a4.w, b4.z, acc[3][2]); acc[3][3] = fdot2u(a4.w, b4.w, acc[3][3]);
        }
        __syncthreads();
    }

    const float4 bv = *(const float4*)(bias + bn * TN + n0);
#pragma unroll
    for (int i = 0; i < 4; i++) {
        float4 v;
        v.x = acc[i][0] + bv.x;
        v.y = acc[i][1] + bv.y;
        v.z = acc[i][2] + bv.z;
        v.w = acc[i][3] + bv.w;
        *(float4*)&C[(size_t)(row0 + m0 + i) * N + bn * TN + n0] = v;
    }
}

// ---------------------------------------------------------------------------
// LSTM recurrence v16 (UNCHANGED from r7, measured 705us/dispatch): v13
// 2-phase structure + pinned-register U + conflict-free zpart. Used for
// layers 0/1 (HN=256, 4-way split, tagged L2 exchange).
// NOTE (r8): lambda-structured variants (v14/v15/v17) all demote ur[] to
// scratch (VGPR 60, VALUBusy 6%) -- keep phase bodies INLINE.
// ---------------------------------------------------------------------------
template <int HN, bool F16>
__global__ __launch_bounds__(1024, 4) void lstm_rec_v16(
    const float* __restrict__ xz,       // [B, T, 4*HN]
    const float* __restrict__ U,        // [HN, 4*HN]
    float* __restrict__ hout,           // [B, T, HN] or nullptr
    float* __restrict__ out_last,       // [B, HN] or nullptr
    unsigned int* __restrict__ hbuf)    // [2][B_*HN] tagged words
{
    constexpr int GATES = 4 * HN;
    constexpr int COLS = HN;
    constexpr int CP = COLS / 2;
    constexpr int NKG = 1024 / CP;
    constexpr int KH = HN / NKG;
    constexpr int HB = HN / 4;
    constexpr int KWORDS = F16 ? HN / 2 : HN;
    constexpr int WPT = F16 ? KH / 2 : KH;
    constexpr int COLSP = COLS + 2;
    constexpr int NR = 3 * HB / 2;

    __shared__ __align__(16) unsigned int hW[KWORDS];
    __shared__ __align__(16) float zpS[NKG * COLSP];

    const int tid = threadIdx.x;
    const int q = blockIdx.x >> 6;      // quarter 0..3
    const int b = blockIdx.x & 63;      // batch element (siblings 64 apart -> same XCD)

    const int cp = tid % CP;
    const int kq = tid / CP;            // wave-uniform (CP % 64 == 0)
    const int c0 = 2 * cp;
    const int group = c0 / HB;
    const int gcol = group * HN + q * HB + (c0 % HB);
    const int wbase = kq * WPT;

    // ---- one-time: load this thread's U slice into REGISTERS, then PIN ----
    uint2 ur[WPT];
#pragma unroll
    for (int j = 0; j < WPT; ++j) {
        const int w = wbase + j;
        if constexpr (F16) {
            const float2 r0 = *(const float2*)(U + (size_t)(2 * w) * GATES + gcol);
            const float2 r1 = *(const float2*)(U + (size_t)(2 * w + 1) * GATES + gcol);
            ur[j].x = pack_h2(r0.x, r1.x);
            ur[j].y = pack_h2(r0.y, r1.y);
        } else {
            const float2 r0 = *(const float2*)(U + (size_t)w * GATES + gcol);
            ur[j].x = __builtin_bit_cast(unsigned int, r0.x);
            ur[j].y = __builtin_bit_cast(unsigned int, r0.y);
        }
    }
#pragma unroll
    for (int j = 0; j < WPT; ++j)
        asm volatile("" : "+v"(ur[j].x), "+v"(ur[j].y));

    if (tid < KWORDS) hW[tid] = 0u;     // h_0 = 0
    float cst = 0.f;

    const float* xzcell = xz + (size_t)b * T_ * GATES + q * HB + tid;
    float z4[4] = {0.f, 0.f, 0.f, 0.f};
    if (tid < HB) {
#pragma unroll
        for (int g = 0; g < 4; ++g) z4[g] = xzcell[(size_t)g * HN];   // t=0
    }
    __syncthreads();   // one-time init barrier

#pragma unroll 1
    for (int t = 0; t < T_; ++t) {
        // ---- phase A: dot (U in regs, h from LDS) ----
        float acc0 = 0.f, acc1 = 0.f;
#pragma unroll
        for (int j = 0; j < WPT; j += 4) {
            const int w = wbase + j;
            const uint4 hw4 = *(const uint4*)&hW[w];    // wave-uniform broadcast
            if constexpr (F16) {
                acc0 = fdot2u(ur[j + 0].x, hw4.x, acc0); acc1 = fdot2u(ur[j + 0].y, hw4.x, acc1);
                acc0 = fdot2u(ur[j + 1].x, hw4.y, acc0); acc1 = fdot2u(ur[j + 1].y, hw4.y, acc1);
                acc0 = fdot2u(ur[j + 2].x, hw4.z, acc0); acc1 = fdot2u(ur[j + 2].y, hw4.z, acc1);
                acc0 = fdot2u(ur[j + 3].x, hw4.w, acc0); acc1 = fdot2u(ur[j + 3].y, hw4.w, acc1);
            } else {
                acc0 += ubits(ur[j + 0].x) * ubits(hw4.x); acc1 += ubits(ur[j + 0].y) * ubits(hw4.x);
                acc0 += ubits(ur[j + 1].x) * ubits(hw4.y); acc1 += ubits(ur[j + 1].y) * ubits(hw4.y);
                acc0 += ubits(ur[j + 2].x) * ubits(hw4.z); acc1 += ubits(ur[j + 2].y) * ubits(hw4.z);
                acc0 += ubits(ur[j + 3].x) * ubits(hw4.w); acc1 += ubits(ur[j + 3].y) * ubits(hw4.w);
            }
        }
        *(float2*)&zpS[kq * COLSP + c0] = make_float2(acc0, acc1);
        bar_lds();          // bar1

        const unsigned int tag = (unsigned int)(t + 1);
        unsigned int* hslot = hbuf + (size_t)(t & 1) * B_ * HN + b * HN;

        if (tid < HB) {
            float zg[4];
#pragma unroll
            for (int g = 0; g < 4; ++g) {
                float zs = z4[g];
#pragma unroll
                for (int r = 0; r < NKG; ++r) zs += zpS[r * COLSP + g * HB + tid];
                zg[g] = zs;
            }
            if (t + 1 < T_) {
#pragma unroll
                for (int g = 0; g < 4; ++g)
                    z4[g] = xzcell[(size_t)(t + 1) * GATES + (size_t)g * HN];
            }
            const float ig = fsig(zg[0]);
            const float fg = fsig(zg[1]);
            const float gg = ftanh(zg[2]);
            const float og = fsig(zg[3]);
            cst = fg * cst + ig * gg;
            const float hnew = og * ftanh(cst);

            if (hout) hout[((size_t)b * T_ + t) * HN + q * HB + tid] = hnew;
            if (t == T_ - 1) {
                if (out_last) out_last[(size_t)b * HN + q * HB + tid] = hnew;
            } else {
                const unsigned short h16 = f2h_bits(hnew);
                __hip_atomic_store(&hslot[q * HB + tid],
                                   ((unsigned int)tag << 16) | (unsigned int)h16,
                                   __ATOMIC_RELAXED, __HIP_MEMORY_SCOPE_AGENT);
                if constexpr (F16) {
                    reinterpret_cast<unsigned short*>(hW)[q * HB + tid] = h16;
                } else {
                    hW[q * HB + tid] = __builtin_bit_cast(unsigned int, hnew);
                }
            }
        } else if (tid >= 64 && tid < 64 + NR && t < T_ - 1) {
            const int idx = tid - 64;
            const int qp0 = q * (HB / 2);
            const int p = idx + (idx >= qp0 ? (HB / 2) : 0);   // remote pair index
            const unsigned long long* hq = (const unsigned long long*)hslot;
            unsigned long long v = __hip_atomic_load(&hq[p],
                __ATOMIC_RELAXED, __HIP_MEMORY_SCOPE_AGENT);
            while (((v >> 16) & 0xffffu) != tag || (v >> 48) != tag)
                v = __hip_atomic_load(&hq[p],
                    __ATOMIC_RELAXED, __HIP_MEMORY_SCOPE_AGENT);
            if constexpr (F16) {
                hW[p] = (unsigned int)(v & 0xffffu) |
                        ((unsigned int)((v >> 32) & 0xffffu) << 16);
            } else {
                hW[2 * p + 0] = __builtin_bit_cast(unsigned int, h2f_bits((unsigned int)v));
                hW[2 * p + 1] = __builtin_bit_cast(unsigned int, h2f_bits((unsigned int)(v >> 32)));
            }
        }
        bar_lds();          // bar2
    }
}

// ---------------------------------------------------------------------------
// LSTM recurrence v18-full: ONE block per batch element, NO exchange.
// For HN=128 (layer 2): the full hidden state (512 gate-cols x K=128) fits
// one 1024-thread block -- ur = 64 f32 VGPRs/thread under the 128 cap of
// (1024,4). h lives entirely in LDS: the publish/L2-visibility/poll/skew
// chain (r7: ~2/3 of the 3305cy step) vanishes. Step = dot -> bar -> cell
// -> bar. 64 blocks (1/4 chip) is fine: the recurrence is latency-bound.
// Geometry: COLS=512 (local col == global col since block owns all units),
// CP=256, NKG=4, KH=32, WPT=32. Inline bodies (no lambdas -- r8 lesson).
// ---------------------------------------------------------------------------
__global__ __launch_bounds__(1024, 4) void lstm_full_v18(
    const float* __restrict__ xz,       // [B, T, 512]
    const float* __restrict__ U,        // [128, 512]
    float* __restrict__ out_last)       // [B, 128]
{
    constexpr int HN = 128;
    constexpr int GATES = 512;
    constexpr int COLS = 512;           // all 4 gates x 128 units
    constexpr int CP = COLS / 2;        // 256 col-pairs
    constexpr int NKG = 1024 / CP;      // 4 k-groups
    constexpr int KH = HN / NKG;        // 32 k per group
    constexpr int WPT = KH;             // 32 ur entries (f32 pairs)
    constexpr int KWORDS = HN;          // 128 f32 h words
    constexpr int COLSP = COLS + 2;     // 514

    __shared__ __align__(16) unsigned int hW[KWORDS];
    __shared__ __align__(16) float zpS[NKG * COLSP];

    const int tid = threadIdx.x;
    const int b = blockIdx.x;           // batch element

    const int cp = tid % CP;
    const int kq = tid / CP;            // wave-uniform (CP = 256)
    const int c0 = 2 * cp;              // local col == global gate-col
    const int wbase = kq * WPT;

    // ---- one-time: U slice into registers (2 cols x 32 k = 64 f32), PIN ----
    uint2 ur[WPT];
#pragma unroll
    for (int j = 0; j < WPT; ++j) {
        const int w = wbase + j;
        const float2 r0 = *(const float2*)(U + (size_t)w * GATES + c0);
        ur[j].x = __builtin_bit_cast(unsigned int, r0.x);
        ur[j].y = __builtin_bit_cast(unsigned int, r0.y);
    }
#pragma unroll
    for (int j = 0; j < WPT; ++j)
        asm volatile("" : "+v"(ur[j].x), "+v"(ur[j].y));

    if (tid < KWORDS) hW[tid] = 0u;     // h_0 = 0
    float cst = 0.f;

    // cell lane: thread u (< 128) owns unit u; xz cols g*128 + u
    const float* xzcell = xz + (size_t)b * T_ * GATES + tid;
    float z4[4] = {0.f, 0.f, 0.f, 0.f};
    if (tid < HN) {
#pragma unroll
        for (int g = 0; g < 4; ++g) z4[g] = xzcell[g * HN];   // t=0
    }
    __syncthreads();   // one-time init barrier

#pragma unroll 1
    for (int t = 0; t < T_; ++t) {
        // ---- phase A: dot over this thread's 32 k (U in regs, h in LDS) ----
        float acc0 = 0.f, acc1 = 0.f;
#pragma unroll
        for (int j = 0; j < WPT; j += 4) {
            const int w = wbase + j;
            const uint4 hw4 = *(const uint4*)&hW[w];    // wave-uniform broadcast
            acc0 += ubits(ur[j + 0].x) * ubits(hw4.x); acc1 += ubits(ur[j + 0].y) * ubits(hw4.x);
            acc0 += ubits(ur[j + 1].x) * ubits(hw4.y); acc1 += ubits(ur[j + 1].y) * ubits(hw4.y);
            acc0 += ubits(ur[j + 2].x) * ubits(hw4.z); acc1 += ubits(ur[j + 2].y) * ubits(hw4.z);
            acc0 += ubits(ur[j + 3].x) * ubits(hw4.w); acc1 += ubits(ur[j + 3].y) * ubits(hw4.w);
        }
        *(float2*)&zpS[kq * COLSP + c0] = make_float2(acc0, acc1);
        bar_lds();          // bar1

        // ---- phase B: cell update (threads < 128), h stays in LDS ----
        if (tid < HN) {
            float zg[4];
#pragma unroll
            for (int g = 0; g < 4; ++g) {
                float zs = z4[g];
#pragma unroll
                for (int r = 0; r < NKG; ++r) zs += zpS[r * COLSP + g * HN + tid];
                zg[g] = zs;
            }
            if (t + 1 < T_) {   // prefetch next xz
#pragma unroll
                for (int g = 0; g < 4; ++g)
                    z4[g] = xzcell[(size_t)(t + 1) * GATES + g * HN];
            }
            const float ig = fsig(zg[0]);
            const float fg = fsig(zg[1]);
            const float gg = ftanh(zg[2]);
            const float og = fsig(zg[3]);
            cst = fg * cst + ig * gg;
            const float hnew = og * ftanh(cst);

            if (t == T_ - 1) {
                out_last[(size_t)b * HN + tid] = hnew;
            } else {
                hW[tid] = __builtin_bit_cast(unsigned int, hnew);
            }
        }
        bar_lds();          // bar2 -> next dot sees h(t+1)
    }
}

// ---------------------------------------------------------------------------
// Launch
// ---------------------------------------------------------------------------
extern "C" void kernel_launch(void* const* d_in, const int* in_sizes, int n_in,
                              void* d_out, int out_size, void* d_ws, size_t ws_size,
                              hipStream_t stream)
{
    const float* x  = (const float*)d_in[0];
    const float* W0 = (const float*)d_in[1];
    const float* U0 = (const float*)d_in[2];
    const float* b0 = (const float*)d_in[3];
    const float* W1 = (const float*)d_in[4];
    const float* U1 = (const float*)d_in[5];
    const float* b1 = (const float*)d_in[6];
    const float* W2 = (const float*)d_in[7];
    const float* U2 = (const float*)d_in[8];
    const float* b2 = (const float*)d_in[9];
    const float* m0 = (const float*)d_in[10];
    const float* m1 = (const float*)d_in[11];
    const float* m2 = (const float*)d_in[12];
    float* out = (float*)d_out;

    // workspace layout:
    //   xz    : 134217728 B   (64*512*1024 floats, reused by all 3 layers)
    //   h0    :  33554432 B
    //   h1    :  33554432 B
    //   hbuf  : 3 regions x 131072 B (2 x 64 x 256 tagged words per layer)
    char* ws = (char*)d_ws;
    float* xz = (float*)ws;
    float* h0 = (float*)(ws + 134217728);
    float* h1 = (float*)(ws + 134217728 + 33554432);
    unsigned int* hb0 = (unsigned int*)(ws + 134217728 + 2 * 33554432);
    unsigned int* hb1 = hb0 + 2 * B_ * 256;

    const int M = B_ * T_;  // 32768

    // Layer 0
    gemm_mask_f16<<<dim3(1024 / 64, M / 64), 256, 0, stream>>>(x, W0, b0, m0, xz, M, 1024, 128);
    lstm_rec_v16<256, true><<<256, 1024, 0, stream>>>(xz, U0, h0, nullptr, hb0);

    // Layer 1
    gemm_mask_f16<<<dim3(1024 / 64, M / 64), 256, 0, stream>>>(h0, W1, b1, m1, xz, M, 1024, 256);
    lstm_rec_v16<256, true><<<256, 1024, 0, stream>>>(xz, U1, h1, nullptr, hb1);

    // Layer 2 (H=128): one block per batch, NO exchange, h in LDS
    gemm_mask_f16<<<dim3(512 / 64, M / 64), 256, 0, stream>>>(h1, W2, b2, m2, xz, M, 512, 256);
    lstm_full_v18<<<64, 1024, 0, stream>>>(xz, U2, out);
}